// Round 1
// 270.009 us; speedup vs baseline: 1.0394x; 1.0394x over previous
//
#include <hip/hip_runtime.h>
#include <hip/hip_bf16.h>
#include <cmath>

#define NSP 119
#define UNITS 512
#define NFEAT 360
#define KP1 384          // NFEAT padded to multiple of 32

typedef __attribute__((ext_vector_type(8))) short short8;
typedef __attribute__((ext_vector_type(4))) float floatx4;

// ---------- constant index tables ----------
__constant__ int T2I[15] = {0,1,1,2,2,2,3,3,3,3,4,4,4,4,4};
__constant__ int T2J[15] = {0,0,1,0,1,2,0,1,2,3,0,1,2,3,4};
__constant__ int T3A[35] = {0, 1,1,1, 2,2,2,2,2,2, 3,3,3,3,3,3,3,3,3,3, 4,4,4,4,4,4,4,4,4,4,4,4,4,4,4};
__constant__ int T3B[35] = {0, 0,1,1, 0,1,1,2,2,2, 0,1,1,2,2,2,3,3,3,3, 0,1,1,2,2,2,3,3,3,3,4,4,4,4,4};
__constant__ int T3C[35] = {0, 0,0,1, 0,0,1,0,1,2, 0,0,1,0,1,2,0,1,2,3, 0,0,1,0,1,2,0,1,2,3,0,1,2,3,4};
__constant__ int P2X[6] = {0,1,1,2,2,2};
__constant__ int P2Y[6] = {0,0,1,0,1,2};
__constant__ int P3X[10] = {0,1,1,1,2,2,2,2,2,2};
__constant__ int P3Y[10] = {0,0,1,1,0,1,1,2,2,2};
__constant__ int P3Z[10] = {0,0,0,1,0,0,1,0,1,2};

struct BasisConsts {
    float f0k;      // -betta * log2(e)
    float kg;       // 2*betta*delta*log2(e)
    float scale;    // rad_norm / sqrt(7)
    float c[6];     // exp(-betta*delta*(1 + delta*(2b+1)))
};

// ---------- phase 1a: histogram of in-cutoff pairs per center atom ----------
__global__ __launch_bounds__(256) void hist_kernel(
    const float* __restrict__ R, const int* __restrict__ nbr,
    const float* __restrict__ offsets, int* __restrict__ counts, int npairs)
{
    int p = blockIdx.x * 256 + threadIdx.x;
    if (p >= npairs) return;
    int i = nbr[p];
    int j = nbr[npairs + p];
    float dx = R[3*j]   - R[3*i]   + offsets[3*p];
    float dy = R[3*j+1] - R[3*i+1] + offsets[3*p+1];
    float dz = R[3*j+2] - R[3*i+2] + offsets[3*p+2];
    float dr2 = fmaf(dz, dz, fmaf(dy, dy, dx*dx));   // identical form in scatter_pair!
    if (dr2 < 36.0f) atomicAdd(&counts[i], 1);
}

// ---------- phase 1b: exclusive scan, single block, 32 items/thread ----------
__global__ __launch_bounds__(1024) void scan_kernel(
    const int* __restrict__ counts, int* __restrict__ offs,
    int* __restrict__ cursor, int n)
{
    int tid = threadIdx.x;
    int lane = tid & 63, wid = tid >> 6;
    int beg = tid * 32;
    int local[32];
    int s = 0;
    #pragma unroll
    for (int k = 0; k < 32; ++k) {
        int idx = beg + k;
        int v = (idx < n) ? counts[idx] : 0;
        local[k] = s;
        s += v;
    }
    int incl = s;
    #pragma unroll
    for (int off = 1; off < 64; off <<= 1) {
        int t = __shfl_up(incl, off, 64);
        if (lane >= off) incl += t;
    }
    __shared__ int wsum[16];
    if (lane == 63) wsum[wid] = incl;
    __syncthreads();
    if (tid < 16) {
        int v = wsum[tid];
        int inc2 = v;
        #pragma unroll
        for (int off = 1; off < 16; off <<= 1) {
            int t = __shfl_up(inc2, off, 64);
            if (tid >= off) inc2 += t;
        }
        wsum[tid] = inc2 - v;
    }
    __syncthreads();
    int base = wsum[wid] + (incl - s);
    #pragma unroll
    for (int k = 0; k < 32; ++k) {
        int idx = beg + k;
        if (idx < n) { int v = base + local[k]; offs[idx] = v; cursor[idx] = v; }
    }
}

// ---------- phase 1c (fused): scatter + per-pair record compute ----------
// rad basis via geometric recurrence: 2 exp2 + 1 native cos + sqrt instead of
// 7 expf + libm cosf + expf(logf(..)).
__global__ __launch_bounds__(256) void scatter_pair_kernel(
    const float* __restrict__ R, const int* __restrict__ Z,
    const int* __restrict__ nbr, const float* __restrict__ offsets,
    const float* __restrict__ emb, int* __restrict__ cursor,
    float* __restrict__ pairdata, int npairs, BasisConsts bc)
{
    int p = blockIdx.x * 256 + threadIdx.x;
    if (p >= npairs) return;
    int i = nbr[p];
    int j = nbr[npairs + p];
    float dx = R[3*j]   - R[3*i]   + offsets[3*p];
    float dy = R[3*j+1] - R[3*i+1] + offsets[3*p+1];
    float dz = R[3*j+2] - R[3*i+2] + offsets[3*p+2];
    float dr2 = fmaf(dz, dz, fmaf(dy, dy, dx*dx));   // identical form in hist!
    if (dr2 >= 36.0f) return;
    int pos = atomicAdd(&cursor[i], 1);

    float dr  = sqrtf(dr2);
    float inv = 1.0f / (dr + 1e-5f);
    float d0  = dr - 0.5f;
    float basis[7];
    basis[0] = exp2f(bc.f0k * d0 * d0);
    float G  = exp2f(bc.kg * dr);
    float cur = basis[0];
    #pragma unroll
    for (int b = 0; b < 6; ++b) { cur *= G * bc.c[b]; basis[b+1] = cur; }
    float cut = 0.5f * (__cosf(dr * 0.52359877559829887f) + 1.0f);  // pi/R_MAX
    float s = bc.scale * cut;

    const float* e = emb + ((size_t)Z[j] * NSP + Z[i]) * 35;
    float ev[35];
    __builtin_memcpy(ev, e, 35 * sizeof(float));

    float rec[8];
    #pragma unroll
    for (int r = 0; r < 5; ++r) {
        float acc = 0.f;
        #pragma unroll
        for (int b = 0; b < 7; ++b) acc += ev[r*7+b] * basis[b];
        rec[r] = s * acc;
    }
    rec[5] = dx * inv; rec[6] = dy * inv; rec[7] = dz * inv;
    float4* out = (float4*)(pairdata + (size_t)pos * 8);
    out[0] = make_float4(rec[0], rec[1], rec[2], rec[3]);
    out[1] = make_float4(rec[4], rec[5], rec[6], rec[7]);
}

// ---------- phase 2: one wave per atom: moments + contractions -> 360 bf16 feats ----------
// Padded, 16B-aligned LDS layout so all contractions use ds_read_b128 row-dots:
//   M0 at 0 (8), M1 at 8 ([5][4]), M2 at 28 ([5][12]), M3 at 88 ([5][28]),
//   M3T at 228 ([3][5][12], z-major).  Pads are zero so vector dots are exact.
#define SREC 12   // stage record stride (floats); [0..4]=rad, [5..7]=dn, [8]=1.0
#define FM1  8
#define FM2  28
#define FM3  88
#define FM3T 228
#define FTOT 416

__device__ __forceinline__ float dot4(float4 a, float4 b) {
    return a.x*b.x + a.y*b.y + a.z*b.z + a.w*b.w;
}
__device__ __forceinline__ float dot12(const float4* a, const float4* b) {
    return dot4(a[0], b[0]) + dot4(a[1], b[1]) + dot4(a[2], b[2]);
}

__global__ __launch_bounds__(256) void moment_feat_kernel(
    const float* __restrict__ pairdata, const int* __restrict__ offs,
    const int* __restrict__ counts, __hip_bfloat16* __restrict__ feats, int natoms)
{
    int wv = threadIdx.x >> 6, lane = threadIdx.x & 63;
    int a = blockIdx.x * 4 + wv;
    __shared__ float stage[4][64][SREC];
    __shared__ __align__(16) float F[4][FTOT];
    __shared__ __align__(16) float B2s[4][192];   // [15][12], cols 9..11 zero
    __shared__ __align__(16) float A3s[4][100];   // [25][4],  col 3 zero
    if (a >= natoms) return;   // wave-uniform; no __syncthreads in this kernel

    int start = offs[a], cnt = counts[a];

    int cr0, f00 = 8, f01 = 8, f02 = 8;
    if (lane < 5)       { cr0 = lane; }
    else if (lane < 20) { int c = lane - 5;  cr0 = c / 3; f00 = 5 + c % 3; }
    else if (lane < 50) { int c = lane - 20; cr0 = c / 6; int k = c % 6;
                          f00 = 5 + P2X[k]; f01 = 5 + P2Y[k]; }
    else                { int c = lane - 50; cr0 = c / 10; int k = c % 10;
                          f00 = 5 + P3X[k]; f01 = 5 + P3Y[k]; f02 = 5 + P3Z[k]; }
    int cr1 = 8, f10 = 8, f11 = 8, f12 = 8;
    if (lane < 36) { int c = 14 + lane; cr1 = c / 10; int k = c % 10;
                     f10 = 5 + P3X[k]; f11 = 5 + P3Y[k]; f12 = 5 + P3Z[k]; }

    float acc0 = 0.f, acc1 = 0.f;
    for (int base = 0; base < cnt; base += 64) {
        int m = min(64, cnt - base);
        if (lane < m) {
            const float4* pd = (const float4*)(pairdata + (size_t)(start + base + lane) * 8);
            float4 u = pd[0], v = pd[1];
            float* st = stage[wv][lane];
            ((float4*)st)[0] = u;
            ((float4*)st)[1] = v;
            st[8] = 1.0f;
        }
        __builtin_amdgcn_wave_barrier();
        for (int q = 0; q < m; ++q) {
            const float* s = stage[wv][q];
            acc0 += s[cr0] * s[f00] * s[f01] * s[f02];
            acc1 += s[cr1] * s[f10] * s[f11] * s[f12];
        }
        __builtin_amdgcn_wave_barrier();
    }
    float* raw = &stage[wv][0][0];
    __builtin_amdgcn_wave_barrier();
    raw[lane] = acc0;
    if (lane < 36) raw[64 + lane] = acc1;
    __builtin_amdgcn_wave_barrier();

    // ---- expand compressed moments into padded F layout (+ transposed M3T) ----
    #pragma unroll
    for (int it = 0; it < 7; ++it) {
        int idx = lane + it * 64;
        if (idx < FTOT) {
            float v = 0.f;
            if (idx < 5) {
                v = raw[idx];
            } else if (idx < 8) {
                // pad
            } else if (idx < 28) {            // M1 [5][4]
                int rel = idx - 8, r = rel >> 2, x = rel & 3;
                if (x < 3) v = raw[5 + r*3 + x];
            } else if (idx < 88) {            // M2 [5][12]
                int rel = idx - 28, r = rel / 12, q = rel - r*12;
                if (q < 9) {
                    int x = q / 3, y = q - x*3;
                    int hi = max(x, y), lo = min(x, y);
                    v = raw[20 + r*6 + hi*(hi+1)/2 + lo];
                }
            } else if (idx < 228) {           // M3 [5][28]
                int rel = idx - 88, r = rel / 28, q = rel - r*28;
                if (q < 27) {
                    int x = q / 9, y = (q / 3) % 3, z = q % 3;
                    int A = max(x, max(y, z)), C = min(x, min(y, z)), B = x + y + z - A - C;
                    v = raw[50 + r*10 + A*(A+1)*(A+2)/6 + B*(B+1)/2 + C];
                }
            } else if (idx < 408) {           // M3T [3][5][12]  (z-major)
                int rel = idx - 228, z = rel / 60, rem = rel - z*60;
                int r = rem / 12, q = rem - r*12;
                if (q < 9) {
                    int x = q / 3, y = q - x*3;
                    int A = max(x, max(y, z)), C = min(x, min(y, z)), B = x + y + z - A - C;
                    v = raw[50 + r*10 + A*(A+1)*(A+2)/6 + B*(B+1)/2 + C];
                }
            }
            F[wv][idx] = v;
        }
    }
    __builtin_amdgcn_wave_barrier();

    const float* Fw = F[wv];

    // ---- B2 / A3 precontractions via vector dots over M3T rows ----
    #pragma unroll
    for (int it = 0; it < 5; ++it) {
        int idx = lane + it * 64;
        if (idx < 135) {
            int p = idx / 9, zw = idx - p*9, z = zw / 3, w_ = zw - z*3;
            int r = T2I[p], s = T2J[p];
            const float4* av = (const float4*)(Fw + FM3T + (z*5 + r)*12);
            const float4* bv = (const float4*)(Fw + FM3T + (w_*5 + s)*12);
            B2s[wv][p*12 + zw] = dot12(av, bv);
        } else if (idx < 210) {
            int e2 = idx - 135, rs = e2 / 3, z = e2 - rs*3;
            int r = rs / 5, s = rs - r*5;
            const float4* av = (const float4*)(Fw + FM3T + (z*5 + r)*12);
            const float4* bv = (const float4*)(Fw + FM2 + s*12);
            A3s[wv][rs*4 + z] = dot12(av, bv);
        } else if (idx < 280) {
            int pd = idx - 210;
            if (pd < 45) { int p = pd / 3, c2 = pd - p*3; B2s[wv][p*12 + 9 + c2] = 0.f; }
            else         { int e3 = pd - 45; A3s[wv][e3*4 + 3] = 0.f; }
        }
    }
    __builtin_amdgcn_wave_barrier();

    const float* B2w = B2s[wv];
    const float* A3w = A3s[wv];
    __hip_bfloat16* out = feats + (size_t)a * KP1;
    for (int f = lane; f < NFEAT; f += 64) {
        float v = 0.f;
        if (f < 5) {
            v = Fw[f];
        } else if (f < 20) {                 // c1
            int p = f - 5, r = T2I[p], s = T2J[p];
            v = dot4(*(const float4*)(Fw + FM1 + r*4), *(const float4*)(Fw + FM1 + s*4));
        } else if (f < 35) {                 // c2
            int p = f - 20, r = T2I[p], s = T2J[p];
            v = dot12((const float4*)(Fw + FM2 + r*12), (const float4*)(Fw + FM2 + s*12));
        } else if (f < 50) {                 // c3
            int p = f - 35, r = T2I[p], s = T2J[p];
            const float4* av = (const float4*)(Fw + FM3 + r*28);
            const float4* bv = (const float4*)(Fw + FM3 + s*28);
            v = dot4(av[0],bv[0]) + dot4(av[1],bv[1]) + dot4(av[2],bv[2]) + dot4(av[3],bv[3])
              + dot4(av[4],bv[4]) + dot4(av[5],bv[5]) + dot4(av[6],bv[6]);
        } else if (f < 85) {                 // c4: rows r,s,t of M2 into regs, unrolled 27
            int q = f - 50, r = T3A[q], s = T3B[q], t = T3C[q];
            float ar[12], as_[12], at_[12];
            const float4* rv = (const float4*)(Fw + FM2 + r*12);
            const float4* sv = (const float4*)(Fw + FM2 + s*12);
            const float4* tv = (const float4*)(Fw + FM2 + t*12);
            #pragma unroll
            for (int k = 0; k < 3; ++k) {
                *(float4*)(ar + 4*k)  = rv[k];
                *(float4*)(as_ + 4*k) = sv[k];
                *(float4*)(at_ + 4*k) = tv[k];
            }
            #pragma unroll
            for (int x = 0; x < 3; ++x)
                #pragma unroll
                for (int y = 0; y < 3; ++y) {
                    float d3 = as_[x*3+0]*at_[y*3+0] + as_[x*3+1]*at_[y*3+1]
                             + as_[x*3+2]*at_[y*3+2];
                    v += ar[x*3+y] * d3;
                }
        } else if (f < 160) {                // c5
            int q = f - 85, p = q / 5, t = q - p*5, r = T2I[p], s = T2J[p];
            float4 m1r = *(const float4*)(Fw + FM1 + r*4);
            float4 m1s = *(const float4*)(Fw + FM1 + s*4);
            const float4* mt = (const float4*)(Fw + FM2 + t*12);
            float4 t0 = mt[0], t1 = mt[1], t2 = mt[2];
            v = m1r.x*(m1s.x*t0.x + m1s.y*t0.y + m1s.z*t0.z)
              + m1r.y*(m1s.x*t0.w + m1s.y*t1.x + m1s.z*t1.y)
              + m1r.z*(m1s.x*t1.z + m1s.y*t1.w + m1s.z*t2.x);
        } else if (f < 235) {                // c6 via B2
            int q = f - 160, p = q / 5, t = q - p*5;
            v = dot12((const float4*)(B2w + p*12), (const float4*)(Fw + FM2 + t*12));
        } else {                             // c7 via A3
            int q = f - 235, r = q / 25, s = (q / 5) % 5, t = q - (q / 5)*5;
            v = dot4(*(const float4*)(A3w + (r*5 + s)*4), *(const float4*)(Fw + FM1 + t*4));
        }
        out[f] = __float2bfloat16(v);
    }
    if (lane < KP1 - NFEAT) out[NFEAT + lane] = __float2bfloat16(0.f);
}

// ---------- weight transpose+pad to bf16: Wt[n*Kp+k] = W[k*N+n] ----------
__global__ __launch_bounds__(256) void prep_w_t(
    const float* __restrict__ W, __hip_bfloat16* __restrict__ Wt,
    int K, int N, int Kp)
{
    int idx = blockIdx.x * 256 + threadIdx.x;
    if (idx >= N * Kp) return;
    int n = idx / Kp, k = idx % Kp;
    float v = (k < K) ? W[(size_t)k * N + n] : 0.f;
    Wt[idx] = __float2bfloat16(v);
}

// ---------- bf16 MFMA GEMM, 128x64 tile, BK=32, reg-staged double-buffer ----------
__global__ __launch_bounds__(256) void gemm_mfma_swish(
    const __hip_bfloat16* __restrict__ A, const __hip_bfloat16* __restrict__ Bt,
    const float* __restrict__ bias, __hip_bfloat16* __restrict__ C,
    const float* __restrict__ w3, float* __restrict__ outacc,
    int Kp, int M, float alpha, float a3, int fuse)
{
    __shared__ float4 As[2][512];   // 128 rows x 4 chunks
    __shared__ float4 Bs[2][256];   // 64 rows x 4 chunks
    int tid = threadIdx.x;
    int wave = tid >> 6, lane = tid & 63;
    int quad = lane >> 4, l16 = lane & 15;
    int wm = wave >> 1, wn = wave & 1;   // 2x2 waves: 64-row x 32-col each
    int rowBase = blockIdx.x * 128;
    int colBase = blockIdx.y * 64;

    floatx4 acc[4][2] = {};

    int rA0 = tid >> 2, cA = tid & 3;   // A rows 0..63
    int rA1 = rA0 + 64;                 // A rows 64..127
    int pA0 = rA0 * 4 + (cA ^ ((rA0 >> 1) & 3));
    int pA1 = rA1 * 4 + (cA ^ ((rA1 >> 1) & 3));
    int pB  = rA0 * 4 + (cA ^ ((rA0 >> 1) & 3));

    const char* pa0 = (const char*)(A  + (size_t)(rowBase + rA0) * Kp + cA * 8);
    const char* pa1 = (const char*)(A  + (size_t)(rowBase + rA1) * Kp + cA * 8);
    const char* pb  = (const char*)(Bt + (size_t)(colBase + rA0) * Kp + cA * 8);

    int posA[4], posB[2];
    #pragma unroll
    for (int t = 0; t < 4; ++t) {
        int rr = wm * 64 + t * 16 + l16;
        posA[t] = rr * 4 + (quad ^ ((rr >> 1) & 3));
    }
    #pragma unroll
    for (int u = 0; u < 2; ++u) {
        int cc = wn * 32 + u * 16 + l16;
        posB[u] = cc * 4 + (quad ^ ((cc >> 1) & 3));
    }

    int nK = Kp >> 5;
    float4 ra0 = *(const float4*)pa0;
    float4 ra1 = *(const float4*)pa1;
    float4 rb  = *(const float4*)pb;

    for (int kt = 0; kt < nK; ++kt) {
        int buf = kt & 1;
        As[buf][pA0] = ra0;
        As[buf][pA1] = ra1;
        Bs[buf][pB]  = rb;
        __syncthreads();
        if (kt + 1 < nK) {
            int off = (kt + 1) << 6;   // 32 bf16 = 64 bytes
            ra0 = *(const float4*)(pa0 + off);
            ra1 = *(const float4*)(pa1 + off);
            rb  = *(const float4*)(pb  + off);
        }
        short8 af[4], bf[2];
        #pragma unroll
        for (int t = 0; t < 4; ++t) af[t] = *(const short8*)(As[buf] + posA[t]);
        #pragma unroll
        for (int u = 0; u < 2; ++u) bf[u] = *(const short8*)(Bs[buf] + posB[u]);
        #pragma unroll
        for (int t = 0; t < 4; ++t)
            #pragma unroll
            for (int u = 0; u < 2; ++u)
                acc[t][u] = __builtin_amdgcn_mfma_f32_16x16x32_bf16(
                    af[t], bf[u], acc[t][u], 0, 0, 0);
    }

    if (!fuse) {
        #pragma unroll
        for (int u = 0; u < 2; ++u) {
            int col = colBase + wn * 32 + u * 16 + l16;
            float bc = 0.1f * bias[col];
            #pragma unroll
            for (int t = 0; t < 4; ++t) {
                int row0 = rowBase + wm * 64 + t * 16 + quad * 4;
                #pragma unroll
                for (int r = 0; r < 4; ++r) {
                    float x = alpha * acc[t][u][r] + bc;
                    float v = x / (1.f + expf(-x));
                    C[(size_t)(row0 + r) * UNITS + col] = __float2bfloat16(v);
                }
            }
        }
    } else {
        float rowsum[4][4] = {};
        #pragma unroll
        for (int u = 0; u < 2; ++u) {
            int col = colBase + wn * 32 + u * 16 + l16;
            float bc = 0.1f * bias[col];
            float w3c = w3[col] * a3;
            #pragma unroll
            for (int t = 0; t < 4; ++t)
                #pragma unroll
                for (int r = 0; r < 4; ++r) {
                    float x = alpha * acc[t][u][r] + bc;
                    float v = x / (1.f + expf(-x));
                    rowsum[t][r] += v * w3c;
                }
        }
        #pragma unroll
        for (int t = 0; t < 4; ++t)
            #pragma unroll
            for (int r = 0; r < 4; ++r) {
                float s = rowsum[t][r];
                s += __shfl_xor(s, 1, 64);
                s += __shfl_xor(s, 2, 64);
                s += __shfl_xor(s, 4, 64);
                s += __shfl_xor(s, 8, 64);
                rowsum[t][r] = s;
            }
        if (l16 == 0) {
            #pragma unroll
            for (int t = 0; t < 4; ++t) {
                int row0 = rowBase + wm * 64 + t * 16 + quad * 4;
                #pragma unroll
                for (int r = 0; r < 4; ++r)
                    if (row0 + r < M) atomicAdd(&outacc[row0 + r], rowsum[t][r]);
            }
        }
    }
}

__global__ void finalize_kernel(float* __restrict__ out, const int* __restrict__ Z,
                                const float* __restrict__ b3, int natoms)
{
    int a = blockIdx.x * 256 + threadIdx.x;
    if (a >= natoms) return;
    float v = out[a] + 0.1f * b3[0];
    out[a] = (Z[a] > 0) ? v : 0.f;
}

static inline size_t align_up(size_t x, size_t a) { return (x + a - 1) & ~(a - 1); }

extern "C" void kernel_launch(void* const* d_in, const int* in_sizes, int n_in,
                              void* d_out, int out_size, void* d_ws, size_t ws_size,
                              hipStream_t stream)
{
    const float* R       = (const float*)d_in[0];
    const int*   Z       = (const int*)  d_in[1];
    const int*   nbr     = (const int*)  d_in[2];
    const float* offsets = (const float*)d_in[4];
    const float* emb     = (const float*)d_in[5];
    const float* W1      = (const float*)d_in[6];
    const float* b1      = (const float*)d_in[7];
    const float* W2      = (const float*)d_in[8];
    const float* b2      = (const float*)d_in[9];
    const float* W3      = (const float*)d_in[10];
    const float* b3      = (const float*)d_in[11];

    int natoms = in_sizes[0] / 3;
    int npairs = in_sizes[2] / 2;
    int Mpad = ((natoms + 127) / 128) * 128;

    char* ws = (char*)d_ws;
    size_t off = 0;
    int* counts = (int*)(ws + off); off = align_up(off + natoms*4, 256);
    int* offs   = (int*)(ws + off); off = align_up(off + natoms*4, 256);
    int* cursor = (int*)(ws + off); off = align_up(off + natoms*4, 256);
    float* pairdata = (float*)(ws + off); off = align_up(off + (size_t)npairs*8*4, 256);
    __hip_bfloat16* W1t   = (__hip_bfloat16*)(ws + off); off = align_up(off + (size_t)UNITS*KP1*2, 256);
    __hip_bfloat16* W2t   = (__hip_bfloat16*)(ws + off); off = align_up(off + (size_t)UNITS*UNITS*2, 256);
    __hip_bfloat16* feats = (__hip_bfloat16*)(ws + off); off = align_up(off + (size_t)Mpad*KP1*2, 256);
    __hip_bfloat16* h1    = (__hip_bfloat16*)(ws + off); off = align_up(off + (size_t)Mpad*UNITS*2, 256);

    hipMemsetAsync(counts, 0, (size_t)natoms * sizeof(int), stream);
    hipMemsetAsync(d_out, 0, (size_t)natoms * sizeof(float), stream);

    // host-side double-precision basis constants (exact vs numpy reference)
    BasisConsts bc;
    {
        const double betta = 49.0 / 36.0;
        const double delta = 5.5 / 6.0;
        const double log2e = 1.4426950408889634073599246810;
        bc.f0k = (float)(-betta * log2e);
        bc.kg  = (float)(2.0 * betta * delta * log2e);
        for (int b = 0; b < 6; ++b)
            bc.c[b] = (float)exp(-betta * delta * (1.0 + delta * (2*b + 1)));
        bc.scale = (float)(pow(2.0 * betta / M_PI, 0.75) / sqrt(7.0));
    }

    int pgrid = (npairs + 255) / 256;
    hist_kernel<<<dim3(pgrid), 256, 0, stream>>>(R, nbr, offsets, counts, npairs);
    scan_kernel<<<dim3(1), 1024, 0, stream>>>(counts, offs, cursor, natoms);

    prep_w_t<<<dim3((UNITS*KP1 + 255)/256), 256, 0, stream>>>(W1, W1t, NFEAT, UNITS, KP1);
    prep_w_t<<<dim3((UNITS*UNITS + 255)/256), 256, 0, stream>>>(W2, W2t, UNITS, UNITS, UNITS);

    scatter_pair_kernel<<<dim3(pgrid), 256, 0, stream>>>(
        R, Z, nbr, offsets, emb, cursor, pairdata, npairs, bc);

    moment_feat_kernel<<<dim3((natoms + 3) / 4), 256, 0, stream>>>(
        pairdata, offs, counts, feats, natoms);

    float a1 = 1.0f / sqrtf((float)NFEAT);
    float a2 = 1.0f / sqrtf((float)UNITS);
    dim3 ggrid(Mpad / 128, UNITS / 64);
    gemm_mfma_swish<<<ggrid, 256, 0, stream>>>(
        feats, W1t, b1, h1, nullptr, nullptr, KP1, natoms, a1, 0.f, 0);
    gemm_mfma_swish<<<ggrid, 256, 0, stream>>>(
        h1, W2t, b2, nullptr, W3, (float*)d_out, UNITS, natoms, a2, a2, 1);

    finalize_kernel<<<dim3((natoms + 255) / 256), 256, 0, stream>>>(
        (float*)d_out, Z, b3, natoms);
}

// Round 2
// 248.719 us; speedup vs baseline: 1.1284x; 1.0856x over previous
//
#include <hip/hip_runtime.h>
#include <hip/hip_bf16.h>
#include <cmath>

#define NSP 119
#define UNITS 512
#define NFEAT 360
#define KP1 384          // NFEAT padded to multiple of 32

typedef __attribute__((ext_vector_type(8))) short short8;
typedef __attribute__((ext_vector_type(4))) float floatx4;

// ---------- constant index tables (used by pair/moment kernels) ----------
__constant__ int P2X[6] = {0,1,1,2,2,2};
__constant__ int P2Y[6] = {0,0,1,0,1,2};
__constant__ int P3X[10] = {0,1,1,1,2,2,2,2,2,2};
__constant__ int P3Y[10] = {0,0,1,1,0,1,1,2,2,2};
__constant__ int P3Z[10] = {0,0,0,1,0,0,1,0,1,2};

// compile-time symmetric-index helpers (fold under full unroll)
__device__ __host__ constexpr int s2c(int i, int j) {
    return (i > j) ? i*(i+1)/2 + j : j*(j+1)/2 + i;
}
__device__ __host__ constexpr int s3c(int x, int y, int z) {
    int A = x > y ? x : y; A = A > z ? A : z;
    int C = x < y ? x : y; C = C < z ? C : z;
    int B = x + y + z - A - C;
    return A*(A+1)*(A+2)/6 + B*(B+1)/2 + C;
}

struct BasisConsts {
    float f0k;      // -betta * log2(e)
    float kg;       // 2*betta*delta*log2(e)
    float scale;    // rad_norm / sqrt(7)
    float c[6];     // exp(-betta*delta*(1 + delta*(2b+1)))
};

// ---------- phase 0: fused prep (zero counts/out + both weight transposes) ----------
__global__ __launch_bounds__(256) void prep_kernel(
    const float* __restrict__ W1, const float* __restrict__ W2,
    __hip_bfloat16* __restrict__ W1t, __hip_bfloat16* __restrict__ W2t,
    int* __restrict__ counts, float* __restrict__ outbuf, int natoms)
{
    int idx = blockIdx.x * 256 + threadIdx.x;
    if (idx < UNITS * KP1) {
        int n = idx / KP1, k = idx % KP1;
        W1t[idx] = __float2bfloat16(k < NFEAT ? W1[(size_t)k * UNITS + n] : 0.f);
        return;
    }
    int i2 = idx - UNITS * KP1;
    if (i2 < UNITS * UNITS) {
        int n = i2 / UNITS, k = i2 % UNITS;
        W2t[i2] = __float2bfloat16(W2[(size_t)k * UNITS + n]);
        return;
    }
    int i3 = i2 - UNITS * UNITS;
    if (i3 < natoms) { counts[i3] = 0; outbuf[i3] = 0.f; }
}

// ---------- phase 1a: histogram of in-cutoff pairs per center atom ----------
__global__ __launch_bounds__(256) void hist_kernel(
    const float* __restrict__ R, const int* __restrict__ nbr,
    const float* __restrict__ offsets, int* __restrict__ counts, int npairs)
{
    int p = blockIdx.x * 256 + threadIdx.x;
    if (p >= npairs) return;
    int i = nbr[p];
    int j = nbr[npairs + p];
    float dx = R[3*j]   - R[3*i]   + offsets[3*p];
    float dy = R[3*j+1] - R[3*i+1] + offsets[3*p+1];
    float dz = R[3*j+2] - R[3*i+2] + offsets[3*p+2];
    float dr2 = fmaf(dz, dz, fmaf(dy, dy, dx*dx));   // identical form in scatter_pair!
    if (dr2 < 36.0f) atomicAdd(&counts[i], 1);
}

// ---------- phase 1b: exclusive scan, single block, 32 items/thread ----------
__global__ __launch_bounds__(1024) void scan_kernel(
    const int* __restrict__ counts, int* __restrict__ offs,
    int* __restrict__ cursor, int n)
{
    int tid = threadIdx.x;
    int lane = tid & 63, wid = tid >> 6;
    int beg = tid * 32;
    int local[32];
    int s = 0;
    #pragma unroll
    for (int k = 0; k < 32; ++k) {
        int idx = beg + k;
        int v = (idx < n) ? counts[idx] : 0;
        local[k] = s;
        s += v;
    }
    int incl = s;
    #pragma unroll
    for (int off = 1; off < 64; off <<= 1) {
        int t = __shfl_up(incl, off, 64);
        if (lane >= off) incl += t;
    }
    __shared__ int wsum[16];
    if (lane == 63) wsum[wid] = incl;
    __syncthreads();
    if (tid < 16) {
        int v = wsum[tid];
        int inc2 = v;
        #pragma unroll
        for (int off = 1; off < 16; off <<= 1) {
            int t = __shfl_up(inc2, off, 64);
            if (tid >= off) inc2 += t;
        }
        wsum[tid] = inc2 - v;
    }
    __syncthreads();
    int base = wsum[wid] + (incl - s);
    #pragma unroll
    for (int k = 0; k < 32; ++k) {
        int idx = beg + k;
        if (idx < n) { int v = base + local[k]; offs[idx] = v; cursor[idx] = v; }
    }
}

// ---------- phase 1c (fused): scatter + per-pair record compute ----------
__global__ __launch_bounds__(256) void scatter_pair_kernel(
    const float* __restrict__ R, const int* __restrict__ Z,
    const int* __restrict__ nbr, const float* __restrict__ offsets,
    const float* __restrict__ emb, int* __restrict__ cursor,
    float* __restrict__ pairdata, int npairs, BasisConsts bc)
{
    int p = blockIdx.x * 256 + threadIdx.x;
    if (p >= npairs) return;
    int i = nbr[p];
    int j = nbr[npairs + p];
    float dx = R[3*j]   - R[3*i]   + offsets[3*p];
    float dy = R[3*j+1] - R[3*i+1] + offsets[3*p+1];
    float dz = R[3*j+2] - R[3*i+2] + offsets[3*p+2];
    float dr2 = fmaf(dz, dz, fmaf(dy, dy, dx*dx));   // identical form in hist!
    if (dr2 >= 36.0f) return;
    int pos = atomicAdd(&cursor[i], 1);

    float dr  = sqrtf(dr2);
    float inv = 1.0f / (dr + 1e-5f);
    float d0  = dr - 0.5f;
    float basis[7];
    basis[0] = exp2f(bc.f0k * d0 * d0);
    float G  = exp2f(bc.kg * dr);
    float cur = basis[0];
    #pragma unroll
    for (int b = 0; b < 6; ++b) { cur *= G * bc.c[b]; basis[b+1] = cur; }
    float cut = 0.5f * (__cosf(dr * 0.52359877559829887f) + 1.0f);  // pi/R_MAX
    float s = bc.scale * cut;

    const float* e = emb + ((size_t)Z[j] * NSP + Z[i]) * 35;
    float ev[35];
    __builtin_memcpy(ev, e, 35 * sizeof(float));

    float rec[8];
    #pragma unroll
    for (int r = 0; r < 5; ++r) {
        float acc = 0.f;
        #pragma unroll
        for (int b = 0; b < 7; ++b) acc += ev[r*7+b] * basis[b];
        rec[r] = s * acc;
    }
    rec[5] = dx * inv; rec[6] = dy * inv; rec[7] = dz * inv;
    float4* out = (float4*)(pairdata + (size_t)pos * 8);
    out[0] = make_float4(rec[0], rec[1], rec[2], rec[3]);
    out[1] = make_float4(rec[4], rec[5], rec[6], rec[7]);
}

// ---------- phase 2a: one wave per atom -> 100 compressed moments to global ----------
// momG blocked layout: momG[(a>>6)*6400 + e*64 + (a&63)], e = 0..99
//   e 0..4   : M0[r]
//   e 5..19  : M1[r*3+x]
//   e 20..49 : M2[r*6+s2c]  (sym pairs)
//   e 50..99 : M3[r*10+s3c] (sym triples)
#define SREC 12
__global__ __launch_bounds__(256) void moment_kernel(
    const float* __restrict__ pairdata, const int* __restrict__ offs,
    const int* __restrict__ counts, float* __restrict__ momG, int natoms)
{
    int wv = threadIdx.x >> 6, lane = threadIdx.x & 63;
    int a = blockIdx.x * 4 + wv;
    __shared__ float stage[4][64][SREC];

    int start = 0, cnt = 0;
    if (a < natoms) { start = offs[a]; cnt = counts[a]; }   // pad atoms: zeros

    int cr0, f00 = 8, f01 = 8, f02 = 8;
    if (lane < 5)       { cr0 = lane; }
    else if (lane < 20) { int c = lane - 5;  cr0 = c / 3; f00 = 5 + c % 3; }
    else if (lane < 50) { int c = lane - 20; cr0 = c / 6; int k = c % 6;
                          f00 = 5 + P2X[k]; f01 = 5 + P2Y[k]; }
    else                { int c = lane - 50; cr0 = c / 10; int k = c % 10;
                          f00 = 5 + P3X[k]; f01 = 5 + P3Y[k]; f02 = 5 + P3Z[k]; }
    int cr1 = 8, f10 = 8, f11 = 8, f12 = 8;
    if (lane < 36) { int c = 14 + lane; cr1 = c / 10; int k = c % 10;
                     f10 = 5 + P3X[k]; f11 = 5 + P3Y[k]; f12 = 5 + P3Z[k]; }

    float acc0 = 0.f, acc1 = 0.f;
    for (int base = 0; base < cnt; base += 64) {
        int m = min(64, cnt - base);
        if (lane < m) {
            const float4* pd = (const float4*)(pairdata + (size_t)(start + base + lane) * 8);
            float4 u = pd[0], v = pd[1];
            float* st = stage[wv][lane];
            ((float4*)st)[0] = u;
            ((float4*)st)[1] = v;
            st[8] = 1.0f;
        }
        __builtin_amdgcn_wave_barrier();
        for (int q = 0; q < m; ++q) {
            const float* s = stage[wv][q];
            acc0 += s[cr0] * s[f00] * s[f01] * s[f02];
            acc1 += s[cr1] * s[f10] * s[f11] * s[f12];
        }
        __builtin_amdgcn_wave_barrier();
    }
    size_t base = (size_t)(a >> 6) * 6400 + (size_t)(a & 63);
    momG[base + (size_t)lane * 64] = acc0;
    if (lane < 36) momG[base + (size_t)(64 + lane) * 64] = acc1;
}

// ---------- phase 2b: lane = atom, wave = feature group; all indices constexpr ----------
#define LROW 390   // LDS row stride in bf16: 195 words, 195%32=3 -> conflict-free
__global__ __launch_bounds__(256) void feat_kernel(
    const float* __restrict__ momG, __hip_bfloat16* __restrict__ feats)
{
    constexpr int cT2I[15] = {0,1,1,2,2,2,3,3,3,3,4,4,4,4,4};
    constexpr int cT2J[15] = {0,0,1,0,1,2,0,1,2,3,0,1,2,3,4};
    constexpr int cT3A[35] = {0, 1,1,1, 2,2,2,2,2,2, 3,3,3,3,3,3,3,3,3,3, 4,4,4,4,4,4,4,4,4,4,4,4,4,4,4};
    constexpr int cT3B[35] = {0, 0,1,1, 0,1,1,2,2,2, 0,1,1,2,2,2,3,3,3,3, 0,1,1,2,2,2,3,3,3,3,4,4,4,4,4};
    constexpr int cT3C[35] = {0, 0,0,1, 0,0,1,0,1,2, 0,0,1,0,1,2,0,1,2,3, 0,0,1,0,1,2,0,1,2,3,0,1,2,3,4};
    constexpr float cW2[6]  = {1.f,2.f,1.f,2.f,2.f,1.f};
    constexpr float cW3[10] = {1.f,3.f,3.f,1.f,3.f,6.f,3.f,3.f,3.f,1.f};

    __shared__ __hip_bfloat16 ldsF[64][LROW];
    int wv = threadIdx.x >> 6, lane = threadIdx.x & 63;
    const float* mg = momG + (size_t)blockIdx.x * 6400 + lane;

    #define LDM(e) mg[(e) * 64]
    #define STF(f, v) ldsF[lane][(f)] = __float2bfloat16(v)

    if (wv == 0) {
        // c6 for p = 0..9  -> feats 160 + p*5 + t
        float m3[50], m2[30];
        #pragma unroll
        for (int e = 0; e < 50; ++e) m3[e] = LDM(50 + e);
        #pragma unroll
        for (int e = 0; e < 30; ++e) m2[e] = LDM(20 + e);
        #pragma unroll
        for (int p = 0; p < 10; ++p) {
            int r = cT2I[p], s = cT2J[p];
            float B2v[9];
            #pragma unroll
            for (int z = 0; z < 3; ++z)
                #pragma unroll
                for (int w = 0; w < 3; ++w) {
                    float acc = 0.f;
                    #pragma unroll
                    for (int x = 0; x < 3; ++x)
                        #pragma unroll
                        for (int y = 0; y < 3; ++y)
                            acc += m3[r*10 + s3c(x,y,z)] * m3[s*10 + s3c(x,y,w)];
                    B2v[z*3+w] = acc;
                }
            #pragma unroll
            for (int t = 0; t < 5; ++t) {
                float acc = 0.f;
                #pragma unroll
                for (int z = 0; z < 3; ++z)
                    #pragma unroll
                    for (int w = 0; w < 3; ++w)
                        acc += B2v[z*3+w] * m2[t*6 + s2c(z,w)];
                STF(160 + p*5 + t, acc);
            }
        }
    } else if (wv == 1) {
        // M0, c1, c2, c4, zero-pad
        float m0[5], m1[15], m2[30];
        #pragma unroll
        for (int e = 0; e < 5; ++e)  m0[e] = LDM(e);
        #pragma unroll
        for (int e = 0; e < 15; ++e) m1[e] = LDM(5 + e);
        #pragma unroll
        for (int e = 0; e < 30; ++e) m2[e] = LDM(20 + e);
        #pragma unroll
        for (int r = 0; r < 5; ++r) STF(r, m0[r]);
        #pragma unroll
        for (int p = 0; p < 15; ++p) {
            int r = cT2I[p], s = cT2J[p];
            float v1 = m1[r*3]*m1[s*3] + m1[r*3+1]*m1[s*3+1] + m1[r*3+2]*m1[s*3+2];
            STF(5 + p, v1);
            float v2 = 0.f;
            #pragma unroll
            for (int k = 0; k < 6; ++k) v2 += cW2[k] * m2[r*6+k] * m2[s*6+k];
            STF(20 + p, v2);
        }
        #pragma unroll
        for (int q = 0; q < 35; ++q) {
            int r = cT3A[q], s = cT3B[q], t = cT3C[q];
            float v = 0.f;
            #pragma unroll
            for (int x = 0; x < 3; ++x)
                #pragma unroll
                for (int y = 0; y < 3; ++y) {
                    float d = 0.f;
                    #pragma unroll
                    for (int z = 0; z < 3; ++z)
                        d += m2[s*6 + s2c(x,z)] * m2[t*6 + s2c(y,z)];
                    v += m2[r*6 + s2c(x,y)] * d;
                }
            STF(50 + q, v);
        }
        #pragma unroll
        for (int f = NFEAT; f < KP1; ++f) STF(f, 0.f);
    } else if (wv == 2) {
        // c6 for p = 10..14, plus all of c5
        float m1[15], m2[30], m3[50];
        #pragma unroll
        for (int e = 0; e < 15; ++e) m1[e] = LDM(5 + e);
        #pragma unroll
        for (int e = 0; e < 30; ++e) m2[e] = LDM(20 + e);
        #pragma unroll
        for (int e = 0; e < 50; ++e) m3[e] = LDM(50 + e);
        #pragma unroll
        for (int p = 10; p < 15; ++p) {
            int r = cT2I[p], s = cT2J[p];
            float B2v[9];
            #pragma unroll
            for (int z = 0; z < 3; ++z)
                #pragma unroll
                for (int w = 0; w < 3; ++w) {
                    float acc = 0.f;
                    #pragma unroll
                    for (int x = 0; x < 3; ++x)
                        #pragma unroll
                        for (int y = 0; y < 3; ++y)
                            acc += m3[r*10 + s3c(x,y,z)] * m3[s*10 + s3c(x,y,w)];
                    B2v[z*3+w] = acc;
                }
            #pragma unroll
            for (int t = 0; t < 5; ++t) {
                float acc = 0.f;
                #pragma unroll
                for (int z = 0; z < 3; ++z)
                    #pragma unroll
                    for (int w = 0; w < 3; ++w)
                        acc += B2v[z*3+w] * m2[t*6 + s2c(z,w)];
                STF(160 + p*5 + t, acc);
            }
        }
        #pragma unroll
        for (int p = 0; p < 15; ++p) {
            int r = cT2I[p], s = cT2J[p];
            float o[9];
            #pragma unroll
            for (int x = 0; x < 3; ++x)
                #pragma unroll
                for (int y = 0; y < 3; ++y) o[x*3+y] = m1[r*3+x] * m1[s*3+y];
            #pragma unroll
            for (int t = 0; t < 5; ++t) {
                float v = 0.f;
                #pragma unroll
                for (int x = 0; x < 3; ++x)
                    #pragma unroll
                    for (int y = 0; y < 3; ++y)
                        v += o[x*3+y] * m2[t*6 + s2c(x,y)];
                STF(85 + p*5 + t, v);
            }
        }
    } else {
        // c3, c7
        float m1[15], m2[30], m3[50];
        #pragma unroll
        for (int e = 0; e < 15; ++e) m1[e] = LDM(5 + e);
        #pragma unroll
        for (int e = 0; e < 30; ++e) m2[e] = LDM(20 + e);
        #pragma unroll
        for (int e = 0; e < 50; ++e) m3[e] = LDM(50 + e);
        #pragma unroll
        for (int p = 0; p < 15; ++p) {
            int r = cT2I[p], s = cT2J[p];
            float v = 0.f;
            #pragma unroll
            for (int k = 0; k < 10; ++k) v += cW3[k] * m3[r*10+k] * m3[s*10+k];
            STF(35 + p, v);
        }
        #pragma unroll
        for (int r = 0; r < 5; ++r)
            #pragma unroll
            for (int s = 0; s < 5; ++s) {
                float A3z[3];
                #pragma unroll
                for (int z = 0; z < 3; ++z) {
                    float v = 0.f;
                    #pragma unroll
                    for (int x = 0; x < 3; ++x)
                        #pragma unroll
                        for (int y = 0; y < 3; ++y)
                            v += m3[r*10 + s3c(x,y,z)] * m2[s*6 + s2c(x,y)];
                    A3z[z] = v;
                }
                #pragma unroll
                for (int t = 0; t < 5; ++t) {
                    float v = A3z[0]*m1[t*3] + A3z[1]*m1[t*3+1] + A3z[2]*m1[t*3+2];
                    STF(235 + r*25 + s*5 + t, v);
                }
            }
    }
    __syncthreads();

    // coalesced copy-out: wave wv handles rows wv*16 .. wv*16+15
    __hip_bfloat16* dst = feats + (size_t)blockIdx.x * 64 * KP1;
    #pragma unroll
    for (int rr = 0; rr < 16; ++rr) {
        int row = wv * 16 + rr;
        #pragma unroll
        for (int it = 0; it < 3; ++it) {
            uint32_t v = *(const uint32_t*)&ldsF[row][(it*64 + lane)*2];
            *(uint32_t*)&dst[(size_t)row * KP1 + (size_t)(it*64 + lane)*2] = v;
        }
    }
    #undef LDM
    #undef STF
}

// ---------- bf16 MFMA GEMM, 128x64 tile, BK=32, reg-staged double-buffer ----------
__global__ __launch_bounds__(256) void gemm_mfma_swish(
    const __hip_bfloat16* __restrict__ A, const __hip_bfloat16* __restrict__ Bt,
    const float* __restrict__ bias, __hip_bfloat16* __restrict__ C,
    const float* __restrict__ w3, float* __restrict__ outacc,
    int Kp, int M, float alpha, float a3, int fuse)
{
    __shared__ float4 As[2][512];   // 128 rows x 4 chunks
    __shared__ float4 Bs[2][256];   // 64 rows x 4 chunks
    int tid = threadIdx.x;
    int wave = tid >> 6, lane = tid & 63;
    int quad = lane >> 4, l16 = lane & 15;
    int wm = wave >> 1, wn = wave & 1;   // 2x2 waves: 64-row x 32-col each
    int rowBase = blockIdx.x * 128;
    int colBase = blockIdx.y * 64;

    floatx4 acc[4][2] = {};

    int rA0 = tid >> 2, cA = tid & 3;   // A rows 0..63
    int rA1 = rA0 + 64;                 // A rows 64..127
    int pA0 = rA0 * 4 + (cA ^ ((rA0 >> 1) & 3));
    int pA1 = rA1 * 4 + (cA ^ ((rA1 >> 1) & 3));
    int pB  = rA0 * 4 + (cA ^ ((rA0 >> 1) & 3));

    const char* pa0 = (const char*)(A  + (size_t)(rowBase + rA0) * Kp + cA * 8);
    const char* pa1 = (const char*)(A  + (size_t)(rowBase + rA1) * Kp + cA * 8);
    const char* pb  = (const char*)(Bt + (size_t)(colBase + rA0) * Kp + cA * 8);

    int posA[4], posB[2];
    #pragma unroll
    for (int t = 0; t < 4; ++t) {
        int rr = wm * 64 + t * 16 + l16;
        posA[t] = rr * 4 + (quad ^ ((rr >> 1) & 3));
    }
    #pragma unroll
    for (int u = 0; u < 2; ++u) {
        int cc = wn * 32 + u * 16 + l16;
        posB[u] = cc * 4 + (quad ^ ((cc >> 1) & 3));
    }

    int nK = Kp >> 5;
    float4 ra0 = *(const float4*)pa0;
    float4 ra1 = *(const float4*)pa1;
    float4 rb  = *(const float4*)pb;

    for (int kt = 0; kt < nK; ++kt) {
        int buf = kt & 1;
        As[buf][pA0] = ra0;
        As[buf][pA1] = ra1;
        Bs[buf][pB]  = rb;
        __syncthreads();
        if (kt + 1 < nK) {
            int off = (kt + 1) << 6;   // 32 bf16 = 64 bytes
            ra0 = *(const float4*)(pa0 + off);
            ra1 = *(const float4*)(pa1 + off);
            rb  = *(const float4*)(pb  + off);
        }
        short8 af[4], bf[2];
        #pragma unroll
        for (int t = 0; t < 4; ++t) af[t] = *(const short8*)(As[buf] + posA[t]);
        #pragma unroll
        for (int u = 0; u < 2; ++u) bf[u] = *(const short8*)(Bs[buf] + posB[u]);
        #pragma unroll
        for (int t = 0; t < 4; ++t)
            #pragma unroll
            for (int u = 0; u < 2; ++u)
                acc[t][u] = __builtin_amdgcn_mfma_f32_16x16x32_bf16(
                    af[t], bf[u], acc[t][u], 0, 0, 0);
    }

    if (!fuse) {
        #pragma unroll
        for (int u = 0; u < 2; ++u) {
            int col = colBase + wn * 32 + u * 16 + l16;
            float bc = 0.1f * bias[col];
            #pragma unroll
            for (int t = 0; t < 4; ++t) {
                int row0 = rowBase + wm * 64 + t * 16 + quad * 4;
                #pragma unroll
                for (int r = 0; r < 4; ++r) {
                    float x = alpha * acc[t][u][r] + bc;
                    float v = x / (1.f + expf(-x));
                    C[(size_t)(row0 + r) * UNITS + col] = __float2bfloat16(v);
                }
            }
        }
    } else {
        float rowsum[4][4] = {};
        #pragma unroll
        for (int u = 0; u < 2; ++u) {
            int col = colBase + wn * 32 + u * 16 + l16;
            float bc = 0.1f * bias[col];
            float w3c = w3[col] * a3;
            #pragma unroll
            for (int t = 0; t < 4; ++t)
                #pragma unroll
                for (int r = 0; r < 4; ++r) {
                    float x = alpha * acc[t][u][r] + bc;
                    float v = x / (1.f + expf(-x));
                    rowsum[t][r] += v * w3c;
                }
        }
        #pragma unroll
        for (int t = 0; t < 4; ++t)
            #pragma unroll
            for (int r = 0; r < 4; ++r) {
                float s = rowsum[t][r];
                s += __shfl_xor(s, 1, 64);
                s += __shfl_xor(s, 2, 64);
                s += __shfl_xor(s, 4, 64);
                s += __shfl_xor(s, 8, 64);
                rowsum[t][r] = s;
            }
        if (l16 == 0) {
            #pragma unroll
            for (int t = 0; t < 4; ++t) {
                int row0 = rowBase + wm * 64 + t * 16 + quad * 4;
                #pragma unroll
                for (int r = 0; r < 4; ++r)
                    if (row0 + r < M) atomicAdd(&outacc[row0 + r], rowsum[t][r]);
            }
        }
    }
}

__global__ void finalize_kernel(float* __restrict__ out, const int* __restrict__ Z,
                                const float* __restrict__ b3, int natoms)
{
    int a = blockIdx.x * 256 + threadIdx.x;
    if (a >= natoms) return;
    float v = out[a] + 0.1f * b3[0];
    out[a] = (Z[a] > 0) ? v : 0.f;
}

static inline size_t align_up(size_t x, size_t a) { return (x + a - 1) & ~(a - 1); }

extern "C" void kernel_launch(void* const* d_in, const int* in_sizes, int n_in,
                              void* d_out, int out_size, void* d_ws, size_t ws_size,
                              hipStream_t stream)
{
    const float* R       = (const float*)d_in[0];
    const int*   Z       = (const int*)  d_in[1];
    const int*   nbr     = (const int*)  d_in[2];
    const float* offsets = (const float*)d_in[4];
    const float* emb     = (const float*)d_in[5];
    const float* W1      = (const float*)d_in[6];
    const float* b1      = (const float*)d_in[7];
    const float* W2      = (const float*)d_in[8];
    const float* b2      = (const float*)d_in[9];
    const float* W3      = (const float*)d_in[10];
    const float* b3      = (const float*)d_in[11];

    int natoms = in_sizes[0] / 3;
    int npairs = in_sizes[2] / 2;
    int Mpad = ((natoms + 127) / 128) * 128;

    char* ws = (char*)d_ws;
    size_t off = 0;
    int* counts = (int*)(ws + off); off = align_up(off + natoms*4, 256);
    int* offs   = (int*)(ws + off); off = align_up(off + natoms*4, 256);
    int* cursor = (int*)(ws + off); off = align_up(off + natoms*4, 256);
    float* pairdata = (float*)(ws + off); off = align_up(off + (size_t)npairs*8*4, 256);
    float* momG = (float*)(ws + off); off = align_up(off + (size_t)Mpad*100*4, 256);
    __hip_bfloat16* W1t   = (__hip_bfloat16*)(ws + off); off = align_up(off + (size_t)UNITS*KP1*2, 256);
    __hip_bfloat16* W2t   = (__hip_bfloat16*)(ws + off); off = align_up(off + (size_t)UNITS*UNITS*2, 256);
    __hip_bfloat16* feats = (__hip_bfloat16*)(ws + off); off = align_up(off + (size_t)Mpad*KP1*2, 256);
    __hip_bfloat16* h1    = (__hip_bfloat16*)(ws + off); off = align_up(off + (size_t)Mpad*UNITS*2, 256);

    // host-side double-precision basis constants (exact vs numpy reference)
    BasisConsts bc;
    {
        const double betta = 49.0 / 36.0;
        const double delta = 5.5 / 6.0;
        const double log2e = 1.4426950408889634073599246810;
        bc.f0k = (float)(-betta * log2e);
        bc.kg  = (float)(2.0 * betta * delta * log2e);
        for (int b = 0; b < 6; ++b)
            bc.c[b] = (float)exp(-betta * delta * (1.0 + delta * (2*b + 1)));
        bc.scale = (float)(pow(2.0 * betta / M_PI, 0.75) / sqrt(7.0));
    }

    int prep_items = UNITS*KP1 + UNITS*UNITS + natoms;
    prep_kernel<<<dim3((prep_items + 255)/256), 256, 0, stream>>>(
        W1, W2, W1t, W2t, counts, (float*)d_out, natoms);

    int pgrid = (npairs + 255) / 256;
    hist_kernel<<<dim3(pgrid), 256, 0, stream>>>(R, nbr, offsets, counts, npairs);
    scan_kernel<<<dim3(1), 1024, 0, stream>>>(counts, offs, cursor, natoms);
    scatter_pair_kernel<<<dim3(pgrid), 256, 0, stream>>>(
        R, Z, nbr, offsets, emb, cursor, pairdata, npairs, bc);

    moment_kernel<<<dim3(Mpad / 4), 256, 0, stream>>>(
        pairdata, offs, counts, momG, natoms);
    feat_kernel<<<dim3(Mpad / 64), 256, 0, stream>>>(momG, feats);

    float a1 = 1.0f / sqrtf((float)NFEAT);
    float a2 = 1.0f / sqrtf((float)UNITS);
    dim3 ggrid(Mpad / 128, UNITS / 64);
    gemm_mfma_swish<<<ggrid, 256, 0, stream>>>(
        feats, W1t, b1, h1, nullptr, nullptr, KP1, natoms, a1, 0.f, 0);
    gemm_mfma_swish<<<ggrid, 256, 0, stream>>>(
        h1, W2t, b2, nullptr, W3, (float*)d_out, UNITS, natoms, a2, a2, 1);

    finalize_kernel<<<dim3((natoms + 255) / 256), 256, 0, stream>>>(
        (float*)d_out, Z, b3, natoms);
}

// Round 3
// 214.414 us; speedup vs baseline: 1.3089x; 1.1600x over previous
//
#include <hip/hip_runtime.h>
#include <hip/hip_bf16.h>
#include <cmath>

#define NSP 119
#define UNITS 512
#define NFEAT 360
#define KP1 384          // NFEAT padded to multiple of 32

typedef __attribute__((ext_vector_type(8))) short short8;
typedef __attribute__((ext_vector_type(4))) float floatx4;

// compile-time symmetric-index helpers (fold under full unroll)
__device__ __host__ constexpr int s2c(int i, int j) {
    return (i > j) ? i*(i+1)/2 + j : j*(j+1)/2 + i;
}
__device__ __host__ constexpr int s3c(int x, int y, int z) {
    int A = x > y ? x : y; A = A > z ? A : z;
    int C = x < y ? x : y; C = C < z ? C : z;
    int B = x + y + z - A - C;
    return A*(A+1)*(A+2)/6 + B*(B+1)/2 + C;
}

struct BasisConsts {
    float f0k;      // -betta * log2(e)
    float kg;       // 2*betta*delta*log2(e)
    float scale;    // rad_norm / sqrt(7)
    float c[6];     // exp(-betta*delta*(1 + delta*(2b+1)))
};

// ---------- phase 0: fused prep: tiled W transposes (coalesced) + zero counts/out ----------
// blocks 0..191   : W1 (360x512 -> 512x384 bf16), 12 k-tiles x 16 n-tiles
// blocks 192..447 : W2 (512x512 -> 512x512 bf16), 16 x 16
// blocks 448..    : zero counts + out
__global__ __launch_bounds__(256) void prep_kernel(
    const float* __restrict__ W1, const float* __restrict__ W2,
    __hip_bfloat16* __restrict__ W1t, __hip_bfloat16* __restrict__ W2t,
    int* __restrict__ counts, float* __restrict__ outbuf, int natoms)
{
    int b = blockIdx.x;
    if (b < 448) {
        __shared__ float tile[32][33];
        const float* W; __hip_bfloat16* Wt; int K, Kp, ik, in;
        if (b < 192) { W = W1; Wt = W1t; K = NFEAT; Kp = KP1; ik = b % 12; in = b / 12; }
        else { int b2 = b - 192; W = W2; Wt = W2t; K = UNITS; Kp = UNITS; ik = b2 & 15; in = b2 >> 4; }
        int tx = threadIdx.x & 31, ty = threadIdx.x >> 5;
        int n = in * 32 + tx;                      // N = 512 for both matrices
        #pragma unroll
        for (int pp = 0; pp < 4; ++pp) {
            int kk = ty + pp * 8;
            int k = ik * 32 + kk;
            tile[kk][tx] = (k < K) ? W[(size_t)k * UNITS + n] : 0.f;
        }
        __syncthreads();
        #pragma unroll
        for (int pp = 0; pp < 4; ++pp) {
            int nn = ty + pp * 8;
            Wt[(size_t)(in * 32 + nn) * Kp + ik * 32 + tx] = __float2bfloat16(tile[tx][nn]);
        }
    } else {
        int idx = (b - 448) * 256 + threadIdx.x;
        if (idx < natoms) { counts[idx] = 0; outbuf[idx] = 0.f; }
    }
}

// ---------- phase 1a: histogram of in-cutoff pairs per center atom ----------
__global__ __launch_bounds__(256) void hist_kernel(
    const float* __restrict__ R, const int* __restrict__ nbr,
    const float* __restrict__ offsets, int* __restrict__ counts, int npairs)
{
    int p = blockIdx.x * 256 + threadIdx.x;
    if (p >= npairs) return;
    int i = nbr[p];
    int j = nbr[npairs + p];
    float dx = R[3*j]   - R[3*i]   + offsets[3*p];
    float dy = R[3*j+1] - R[3*i+1] + offsets[3*p+1];
    float dz = R[3*j+2] - R[3*i+2] + offsets[3*p+2];
    float dr2 = fmaf(dz, dz, fmaf(dy, dy, dx*dx));   // identical form in scatter_pair!
    if (dr2 < 36.0f) atomicAdd(&counts[i], 1);
}

// ---------- phase 1b: exclusive scan, single block, 32 items/thread, int4 I/O ----------
__global__ __launch_bounds__(1024) void scan_kernel(
    const int* __restrict__ counts, int* __restrict__ offs,
    int* __restrict__ cursor, int n)
{
    int tid = threadIdx.x;
    int lane = tid & 63, wid = tid >> 6;
    int beg = tid * 32;
    int local[32];
    int s = 0;
    if (beg + 32 <= n) {
        int4 w[8];
        const int4* cp = (const int4*)(counts + beg);
        #pragma unroll
        for (int j = 0; j < 8; ++j) w[j] = cp[j];
        const int* wf = (const int*)w;
        #pragma unroll
        for (int k = 0; k < 32; ++k) { local[k] = s; s += wf[k]; }
    } else {
        #pragma unroll
        for (int k = 0; k < 32; ++k) {
            int idx = beg + k;
            int v = (idx < n) ? counts[idx] : 0;
            local[k] = s; s += v;
        }
    }
    int incl = s;
    #pragma unroll
    for (int off = 1; off < 64; off <<= 1) {
        int t = __shfl_up(incl, off, 64);
        if (lane >= off) incl += t;
    }
    __shared__ int wsum[16];
    if (lane == 63) wsum[wid] = incl;
    __syncthreads();
    if (tid < 16) {
        int v = wsum[tid];
        int inc2 = v;
        #pragma unroll
        for (int off = 1; off < 16; off <<= 1) {
            int t = __shfl_up(inc2, off, 64);
            if (tid >= off) inc2 += t;
        }
        wsum[tid] = inc2 - v;
    }
    __syncthreads();
    int base = wsum[wid] + (incl - s);
    if (beg + 32 <= n) {
        int4* op = (int4*)(offs + beg);
        int4* cp2 = (int4*)(cursor + beg);
        #pragma unroll
        for (int j = 0; j < 8; ++j) {
            int4 t;
            t.x = base + local[j*4];   t.y = base + local[j*4+1];
            t.z = base + local[j*4+2]; t.w = base + local[j*4+3];
            op[j] = t; cp2[j] = t;
        }
    } else {
        #pragma unroll
        for (int k = 0; k < 32; ++k) {
            int idx = beg + k;
            if (idx < n) { int v = base + local[k]; offs[idx] = v; cursor[idx] = v; }
        }
    }
}

// ---------- phase 1c (fused): scatter + per-pair record compute ----------
__global__ __launch_bounds__(256) void scatter_pair_kernel(
    const float* __restrict__ R, const int* __restrict__ Z,
    const int* __restrict__ nbr, const float* __restrict__ offsets,
    const float* __restrict__ emb, int* __restrict__ cursor,
    float* __restrict__ pairdata, int npairs, BasisConsts bc)
{
    int p = blockIdx.x * 256 + threadIdx.x;
    if (p >= npairs) return;
    int i = nbr[p];
    int j = nbr[npairs + p];
    float dx = R[3*j]   - R[3*i]   + offsets[3*p];
    float dy = R[3*j+1] - R[3*i+1] + offsets[3*p+1];
    float dz = R[3*j+2] - R[3*i+2] + offsets[3*p+2];
    float dr2 = fmaf(dz, dz, fmaf(dy, dy, dx*dx));   // identical form in hist!
    if (dr2 >= 36.0f) return;
    int pos = atomicAdd(&cursor[i], 1);

    float dr  = sqrtf(dr2);
    float inv = 1.0f / (dr + 1e-5f);
    float d0  = dr - 0.5f;
    float basis[7];
    basis[0] = exp2f(bc.f0k * d0 * d0);
    float G  = exp2f(bc.kg * dr);
    float cur = basis[0];
    #pragma unroll
    for (int b = 0; b < 6; ++b) { cur *= G * bc.c[b]; basis[b+1] = cur; }
    float cut = 0.5f * (__cosf(dr * 0.52359877559829887f) + 1.0f);  // pi/R_MAX
    float s = bc.scale * cut;

    const float* e = emb + ((size_t)Z[j] * NSP + Z[i]) * 35;
    float ev[35];
    __builtin_memcpy(ev, e, 35 * sizeof(float));

    float rec[8];
    #pragma unroll
    for (int r = 0; r < 5; ++r) {
        float acc = 0.f;
        #pragma unroll
        for (int b = 0; b < 7; ++b) acc += ev[r*7+b] * basis[b];
        rec[r] = s * acc;
    }
    rec[5] = dx * inv; rec[6] = dy * inv; rec[7] = dz * inv;
    float4* out = (float4*)(pairdata + (size_t)pos * 8);
    out[0] = make_float4(rec[0], rec[1], rec[2], rec[3]);
    out[1] = make_float4(rec[4], rec[5], rec[6], rec[7]);
}

// ---------- phase 2a: one wave per atom -> 100 compressed moments to global ----------
// Staged record (28 floats): [0..4]=rad, [5..24]=poly(1, dn, sym2[6], sym3[10]).
// Inner loop: acc += s[cr] * s[5+pk]  (4 LDS reads + 2 FMA per pair, conflict-free).
// momG blocked layout: momG[(a>>6)*6400 + e*64 + (a&63)], e = 0..99
//   e 0..4: M0 | 5..19: M1[r*3+x] | 20..49: M2[r*6+s2c] | 50..99: M3[r*10+s3c]
#define SREC 28
__global__ __launch_bounds__(256) void moment_kernel(
    const float* __restrict__ pairdata, const int* __restrict__ offs,
    const int* __restrict__ counts, float* __restrict__ momG, int natoms)
{
    int wv = threadIdx.x >> 6, lane = threadIdx.x & 63;
    int a = blockIdx.x * 4 + wv;
    __shared__ float stage[4][64][SREC];

    int start = 0, cnt = 0;
    if (a < natoms) { start = offs[a]; cnt = counts[a]; }   // pad atoms: zeros

    // lane -> (cr0, pk0) for moment element e = lane (0..63)
    int cr0, pk0;
    if (lane < 5)       { cr0 = lane;            pk0 = 0; }
    else if (lane < 20) { int c = lane - 5;      cr0 = c / 3;  pk0 = 1 + c % 3; }
    else if (lane < 50) { int c = lane - 20;     cr0 = c / 6;  pk0 = 4 + c % 6; }
    else                { int c = lane - 50;     cr0 = c / 10; pk0 = 10 + c % 10; }
    // lane -> (cr1, pk1) for element e = 64 + lane (lane < 36)
    int cr1 = 0, pk1 = 0;
    if (lane < 36) { int c = 14 + lane; cr1 = c / 10; pk1 = 10 + c % 10; }

    float acc0 = 0.f, acc1 = 0.f;
    for (int base = 0; base < cnt; base += 64) {
        int m = min(64, cnt - base);
        if (lane < m) {
            const float4* pd = (const float4*)(pairdata + (size_t)(start + base + lane) * 8);
            float4 u = pd[0], v = pd[1];
            float x = v.y, y = v.z, z = v.w;
            float s2_0 = x*x, s2_1 = y*x, s2_2 = y*y, s2_3 = z*x, s2_4 = z*y, s2_5 = z*z;
            float* st = stage[wv][lane];
            ((float4*)st)[0] = u;                                    // rad0..3
            ((float4*)st)[1] = make_float4(v.x, 1.0f, x, y);         // rad4, p0=1, p1, p2
            ((float4*)st)[2] = make_float4(z, s2_0, s2_1, s2_2);     // p3..p6
            ((float4*)st)[3] = make_float4(s2_3, s2_4, s2_5, s2_0*x);// p7..p9, p10=xxx
            ((float4*)st)[4] = make_float4(s2_0*y, s2_2*x, s2_2*y, s2_0*z); // p11..p14
            ((float4*)st)[5] = make_float4(s2_1*z, s2_2*z, s2_5*x, s2_5*y); // p15..p18
            ((float4*)st)[6] = make_float4(s2_5*z, 0.f, 0.f, 0.f);   // p19, pad
        }
        __builtin_amdgcn_wave_barrier();
        for (int q = 0; q < m; ++q) {
            const float* s = stage[wv][q];
            acc0 += s[cr0] * s[5 + pk0];
            acc1 += s[cr1] * s[5 + pk1];
        }
        __builtin_amdgcn_wave_barrier();
    }
    size_t base = (size_t)(a >> 6) * 6400 + (size_t)(a & 63);
    momG[base + (size_t)lane * 64] = acc0;
    if (lane < 36) momG[base + (size_t)(64 + lane) * 64] = acc1;
}

// ---------- phase 2b: lane = atom, wave = feature group; all indices constexpr ----------
#define LROW 390   // LDS row stride in bf16: 195 words, 195%32=3 -> conflict-free
__global__ __launch_bounds__(256) void feat_kernel(
    const float* __restrict__ momG, __hip_bfloat16* __restrict__ feats)
{
    constexpr int cT2I[15] = {0,1,1,2,2,2,3,3,3,3,4,4,4,4,4};
    constexpr int cT2J[15] = {0,0,1,0,1,2,0,1,2,3,0,1,2,3,4};
    constexpr int cT3A[35] = {0, 1,1,1, 2,2,2,2,2,2, 3,3,3,3,3,3,3,3,3,3, 4,4,4,4,4,4,4,4,4,4,4,4,4,4,4};
    constexpr int cT3B[35] = {0, 0,1,1, 0,1,1,2,2,2, 0,1,1,2,2,2,3,3,3,3, 0,1,1,2,2,2,3,3,3,3,4,4,4,4,4};
    constexpr int cT3C[35] = {0, 0,0,1, 0,0,1,0,1,2, 0,0,1,0,1,2,0,1,2,3, 0,0,1,0,1,2,0,1,2,3,0,1,2,3,4};
    constexpr float cW2[6]  = {1.f,2.f,1.f,2.f,2.f,1.f};
    constexpr float cW3[10] = {1.f,3.f,3.f,1.f,3.f,6.f,3.f,3.f,3.f,1.f};

    __shared__ __hip_bfloat16 ldsF[64][LROW];
    int wv = threadIdx.x >> 6, lane = threadIdx.x & 63;
    const float* mg = momG + (size_t)blockIdx.x * 6400 + lane;

    #define LDM(e) mg[(e) * 64]
    #define STF(f, v) ldsF[lane][(f)] = __float2bfloat16(v)

    if (wv == 0) {
        // c6 for p = 0..9  -> feats 160 + p*5 + t
        float m3[50], m2[30];
        #pragma unroll
        for (int e = 0; e < 50; ++e) m3[e] = LDM(50 + e);
        #pragma unroll
        for (int e = 0; e < 30; ++e) m2[e] = LDM(20 + e);
        #pragma unroll
        for (int p = 0; p < 10; ++p) {
            int r = cT2I[p], s = cT2J[p];
            float B2v[9];
            #pragma unroll
            for (int z = 0; z < 3; ++z)
                #pragma unroll
                for (int w = 0; w < 3; ++w) {
                    float acc = 0.f;
                    #pragma unroll
                    for (int x = 0; x < 3; ++x)
                        #pragma unroll
                        for (int y = 0; y < 3; ++y)
                            acc += m3[r*10 + s3c(x,y,z)] * m3[s*10 + s3c(x,y,w)];
                    B2v[z*3+w] = acc;
                }
            #pragma unroll
            for (int t = 0; t < 5; ++t) {
                float acc = 0.f;
                #pragma unroll
                for (int z = 0; z < 3; ++z)
                    #pragma unroll
                    for (int w = 0; w < 3; ++w)
                        acc += B2v[z*3+w] * m2[t*6 + s2c(z,w)];
                STF(160 + p*5 + t, acc);
            }
        }
    } else if (wv == 1) {
        // M0, c1, c2, c4, zero-pad
        float m0[5], m1[15], m2[30];
        #pragma unroll
        for (int e = 0; e < 5; ++e)  m0[e] = LDM(e);
        #pragma unroll
        for (int e = 0; e < 15; ++e) m1[e] = LDM(5 + e);
        #pragma unroll
        for (int e = 0; e < 30; ++e) m2[e] = LDM(20 + e);
        #pragma unroll
        for (int r = 0; r < 5; ++r) STF(r, m0[r]);
        #pragma unroll
        for (int p = 0; p < 15; ++p) {
            int r = cT2I[p], s = cT2J[p];
            float v1 = m1[r*3]*m1[s*3] + m1[r*3+1]*m1[s*3+1] + m1[r*3+2]*m1[s*3+2];
            STF(5 + p, v1);
            float v2 = 0.f;
            #pragma unroll
            for (int k = 0; k < 6; ++k) v2 += cW2[k] * m2[r*6+k] * m2[s*6+k];
            STF(20 + p, v2);
        }
        #pragma unroll
        for (int q = 0; q < 35; ++q) {
            int r = cT3A[q], s = cT3B[q], t = cT3C[q];
            float v = 0.f;
            #pragma unroll
            for (int x = 0; x < 3; ++x)
                #pragma unroll
                for (int y = 0; y < 3; ++y) {
                    float d = 0.f;
                    #pragma unroll
                    for (int z = 0; z < 3; ++z)
                        d += m2[s*6 + s2c(x,z)] * m2[t*6 + s2c(y,z)];
                    v += m2[r*6 + s2c(x,y)] * d;
                }
            STF(50 + q, v);
        }
        #pragma unroll
        for (int f = NFEAT; f < KP1; ++f) STF(f, 0.f);
    } else if (wv == 2) {
        // c6 for p = 10..14, plus all of c5
        float m1[15], m2[30], m3[50];
        #pragma unroll
        for (int e = 0; e < 15; ++e) m1[e] = LDM(5 + e);
        #pragma unroll
        for (int e = 0; e < 30; ++e) m2[e] = LDM(20 + e);
        #pragma unroll
        for (int e = 0; e < 50; ++e) m3[e] = LDM(50 + e);
        #pragma unroll
        for (int p = 10; p < 15; ++p) {
            int r = cT2I[p], s = cT2J[p];
            float B2v[9];
            #pragma unroll
            for (int z = 0; z < 3; ++z)
                #pragma unroll
                for (int w = 0; w < 3; ++w) {
                    float acc = 0.f;
                    #pragma unroll
                    for (int x = 0; x < 3; ++x)
                        #pragma unroll
                        for (int y = 0; y < 3; ++y)
                            acc += m3[r*10 + s3c(x,y,z)] * m3[s*10 + s3c(x,y,w)];
                    B2v[z*3+w] = acc;
                }
            #pragma unroll
            for (int t = 0; t < 5; ++t) {
                float acc = 0.f;
                #pragma unroll
                for (int z = 0; z < 3; ++z)
                    #pragma unroll
                    for (int w = 0; w < 3; ++w)
                        acc += B2v[z*3+w] * m2[t*6 + s2c(z,w)];
                STF(160 + p*5 + t, acc);
            }
        }
        #pragma unroll
        for (int p = 0; p < 15; ++p) {
            int r = cT2I[p], s = cT2J[p];
            float o[9];
            #pragma unroll
            for (int x = 0; x < 3; ++x)
                #pragma unroll
                for (int y = 0; y < 3; ++y) o[x*3+y] = m1[r*3+x] * m1[s*3+y];
            #pragma unroll
            for (int t = 0; t < 5; ++t) {
                float v = 0.f;
                #pragma unroll
                for (int x = 0; x < 3; ++x)
                    #pragma unroll
                    for (int y = 0; y < 3; ++y)
                        v += o[x*3+y] * m2[t*6 + s2c(x,y)];
                STF(85 + p*5 + t, v);
            }
        }
    } else {
        // c3, c7
        float m1[15], m2[30], m3[50];
        #pragma unroll
        for (int e = 0; e < 15; ++e) m1[e] = LDM(5 + e);
        #pragma unroll
        for (int e = 0; e < 30; ++e) m2[e] = LDM(20 + e);
        #pragma unroll
        for (int e = 0; e < 50; ++e) m3[e] = LDM(50 + e);
        #pragma unroll
        for (int p = 0; p < 15; ++p) {
            int r = cT2I[p], s = cT2J[p];
            float v = 0.f;
            #pragma unroll
            for (int k = 0; k < 10; ++k) v += cW3[k] * m3[r*10+k] * m3[s*10+k];
            STF(35 + p, v);
        }
        #pragma unroll
        for (int r = 0; r < 5; ++r)
            #pragma unroll
            for (int s = 0; s < 5; ++s) {
                float A3z[3];
                #pragma unroll
                for (int z = 0; z < 3; ++z) {
                    float v = 0.f;
                    #pragma unroll
                    for (int x = 0; x < 3; ++x)
                        #pragma unroll
                        for (int y = 0; y < 3; ++y)
                            v += m3[r*10 + s3c(x,y,z)] * m2[s*6 + s2c(x,y)];
                    A3z[z] = v;
                }
                #pragma unroll
                for (int t = 0; t < 5; ++t) {
                    float v = A3z[0]*m1[t*3] + A3z[1]*m1[t*3+1] + A3z[2]*m1[t*3+2];
                    STF(235 + r*25 + s*5 + t, v);
                }
            }
    }
    __syncthreads();

    // coalesced copy-out: wave wv handles rows wv*16 .. wv*16+15
    __hip_bfloat16* dst = feats + (size_t)blockIdx.x * 64 * KP1;
    #pragma unroll
    for (int rr = 0; rr < 16; ++rr) {
        int row = wv * 16 + rr;
        #pragma unroll
        for (int it = 0; it < 3; ++it) {
            uint32_t v = *(const uint32_t*)&ldsF[row][(it*64 + lane)*2];
            *(uint32_t*)&dst[(size_t)row * KP1 + (size_t)(it*64 + lane)*2] = v;
        }
    }
    #undef LDM
    #undef STF
}

// ---------- bf16 MFMA GEMM, 128x128 tile, BK=32, reg-staged double-buffer ----------
// 1D grid with XCD-grouped swizzle: mt = (bid>>5)*8 + (bid&7), nt = (bid>>3)&3.
// With round-robin block->XCD dispatch, each XCD runs the 4 N-tiles of "its"
// M-tile back-to-back -> A-tile (96-128 KB) stays in that XCD's L2.
__global__ __launch_bounds__(256) void gemm_mfma_swish(
    const __hip_bfloat16* __restrict__ A, const __hip_bfloat16* __restrict__ Bt,
    const float* __restrict__ bias, __hip_bfloat16* __restrict__ C,
    const float* __restrict__ w3, float* __restrict__ outacc,
    int Kp, int M, int Mtiles, float alpha, float a3, int fuse)
{
    __shared__ float4 As[2][512];   // 128 rows x 4 chunks (32 bf16/row)
    __shared__ float4 Bs[2][512];   // 128 rows x 4 chunks
    int tid = threadIdx.x;
    int wave = tid >> 6, lane = tid & 63;
    int quad = lane >> 4, l16 = lane & 15;
    int wm = wave >> 1, wn = wave & 1;   // 2x2 waves: 64-row x 64-col each
    int bid = blockIdx.x;
    int mt = (bid >> 5) * 8 + (bid & 7);
    int nt = (bid >> 3) & 3;
    if (mt >= Mtiles) return;
    int rowBase = mt * 128;
    int colBase = nt * 128;

    floatx4 acc[4][4] = {};

    int rA0 = tid >> 2, cA = tid & 3;   // rows 0..63
    int rA1 = rA0 + 64;                 // rows 64..127
    int pA0 = rA0 * 4 + (cA ^ ((rA0 >> 1) & 3));
    int pA1 = rA1 * 4 + (cA ^ ((rA1 >> 1) & 3));

    const char* pa0 = (const char*)(A  + (size_t)(rowBase + rA0) * Kp + cA * 8);
    const char* pa1 = (const char*)(A  + (size_t)(rowBase + rA1) * Kp + cA * 8);
    const char* pb0 = (const char*)(Bt + (size_t)(colBase + rA0) * Kp + cA * 8);
    const char* pb1 = (const char*)(Bt + (size_t)(colBase + rA1) * Kp + cA * 8);

    int posA[4], posB[4];
    #pragma unroll
    for (int t = 0; t < 4; ++t) {
        int rr = wm * 64 + t * 16 + l16;
        posA[t] = rr * 4 + (quad ^ ((rr >> 1) & 3));
    }
    #pragma unroll
    for (int u = 0; u < 4; ++u) {
        int cc = wn * 64 + u * 16 + l16;
        posB[u] = cc * 4 + (quad ^ ((cc >> 1) & 3));
    }

    int nK = Kp >> 5;
    float4 ra0 = *(const float4*)pa0;
    float4 ra1 = *(const float4*)pa1;
    float4 rb0 = *(const float4*)pb0;
    float4 rb1 = *(const float4*)pb1;

    for (int kt = 0; kt < nK; ++kt) {
        int buf = kt & 1;
        As[buf][pA0] = ra0;
        As[buf][pA1] = ra1;
        Bs[buf][pA0] = rb0;
        Bs[buf][pA1] = rb1;
        __syncthreads();
        if (kt + 1 < nK) {
            int off = (kt + 1) << 6;   // 32 bf16 = 64 bytes
            ra0 = *(const float4*)(pa0 + off);
            ra1 = *(const float4*)(pa1 + off);
            rb0 = *(const float4*)(pb0 + off);
            rb1 = *(const float4*)(pb1 + off);
        }
        short8 af[4], bf[4];
        #pragma unroll
        for (int t = 0; t < 4; ++t) af[t] = *(const short8*)(As[buf] + posA[t]);
        #pragma unroll
        for (int u = 0; u < 4; ++u) bf[u] = *(const short8*)(Bs[buf] + posB[u]);
        #pragma unroll
        for (int t = 0; t < 4; ++t)
            #pragma unroll
            for (int u = 0; u < 4; ++u)
                acc[t][u] = __builtin_amdgcn_mfma_f32_16x16x32_bf16(
                    af[t], bf[u], acc[t][u], 0, 0, 0);
        // no trailing barrier: next iter writes the other LDS buffer
    }

    if (!fuse) {
        #pragma unroll
        for (int u = 0; u < 4; ++u) {
            int col = colBase + wn * 64 + u * 16 + l16;
            float bc = 0.1f * bias[col];
            #pragma unroll
            for (int t = 0; t < 4; ++t) {
                int row0 = rowBase + wm * 64 + t * 16 + quad * 4;
                #pragma unroll
                for (int r = 0; r < 4; ++r) {
                    float x = alpha * acc[t][u][r] + bc;
                    float v = x / (1.f + expf(-x));
                    C[(size_t)(row0 + r) * UNITS + col] = __float2bfloat16(v);
                }
            }
        }
    } else {
        float rowsum[4][4] = {};
        #pragma unroll
        for (int u = 0; u < 4; ++u) {
            int col = colBase + wn * 64 + u * 16 + l16;
            float bc = 0.1f * bias[col];
            float w3c = w3[col] * a3;
            #pragma unroll
            for (int t = 0; t < 4; ++t)
                #pragma unroll
                for (int r = 0; r < 4; ++r) {
                    float x = alpha * acc[t][u][r] + bc;
                    float v = x / (1.f + expf(-x));
                    rowsum[t][r] += v * w3c;
                }
        }
        #pragma unroll
        for (int t = 0; t < 4; ++t)
            #pragma unroll
            for (int r = 0; r < 4; ++r) {
                float s = rowsum[t][r];
                s += __shfl_xor(s, 1, 64);
                s += __shfl_xor(s, 2, 64);
                s += __shfl_xor(s, 4, 64);
                s += __shfl_xor(s, 8, 64);
                rowsum[t][r] = s;
            }
        if (l16 == 0) {
            #pragma unroll
            for (int t = 0; t < 4; ++t) {
                int row0 = rowBase + wm * 64 + t * 16 + quad * 4;
                #pragma unroll
                for (int r = 0; r < 4; ++r)
                    if (row0 + r < M) atomicAdd(&outacc[row0 + r], rowsum[t][r]);
            }
        }
    }
}

__global__ void finalize_kernel(float* __restrict__ out, const int* __restrict__ Z,
                                const float* __restrict__ b3, int natoms)
{
    int a = blockIdx.x * 256 + threadIdx.x;
    if (a >= natoms) return;
    float v = out[a] + 0.1f * b3[0];
    out[a] = (Z[a] > 0) ? v : 0.f;
}

static inline size_t align_up(size_t x, size_t a) { return (x + a - 1) & ~(a - 1); }

extern "C" void kernel_launch(void* const* d_in, const int* in_sizes, int n_in,
                              void* d_out, int out_size, void* d_ws, size_t ws_size,
                              hipStream_t stream)
{
    const float* R       = (const float*)d_in[0];
    const int*   Z       = (const int*)  d_in[1];
    const int*   nbr     = (const int*)  d_in[2];
    const float* offsets = (const float*)d_in[4];
    const float* emb     = (const float*)d_in[5];
    const float* W1      = (const float*)d_in[6];
    const float* b1      = (const float*)d_in[7];
    const float* W2      = (const float*)d_in[8];
    const float* b2      = (const float*)d_in[9];
    const float* W3      = (const float*)d_in[10];
    const float* b3      = (const float*)d_in[11];

    int natoms = in_sizes[0] / 3;
    int npairs = in_sizes[2] / 2;
    int Mpad = ((natoms + 127) / 128) * 128;
    int Mtiles = Mpad / 128;

    char* ws = (char*)d_ws;
    size_t off = 0;
    int* counts = (int*)(ws + off); off = align_up(off + natoms*4, 256);
    int* offs   = (int*)(ws + off); off = align_up(off + natoms*4, 256);
    int* cursor = (int*)(ws + off); off = align_up(off + natoms*4, 256);
    float* pairdata = (float*)(ws + off); off = align_up(off + (size_t)npairs*8*4, 256);
    float* momG = (float*)(ws + off); off = align_up(off + (size_t)Mpad*100*4, 256);
    __hip_bfloat16* W1t   = (__hip_bfloat16*)(ws + off); off = align_up(off + (size_t)UNITS*KP1*2, 256);
    __hip_bfloat16* W2t   = (__hip_bfloat16*)(ws + off); off = align_up(off + (size_t)UNITS*UNITS*2, 256);
    __hip_bfloat16* feats = (__hip_bfloat16*)(ws + off); off = align_up(off + (size_t)Mpad*KP1*2, 256);
    __hip_bfloat16* h1    = (__hip_bfloat16*)(ws + off); off = align_up(off + (size_t)Mpad*UNITS*2, 256);

    // host-side double-precision basis constants (exact vs numpy reference)
    BasisConsts bc;
    {
        const double betta = 49.0 / 36.0;
        const double delta = 5.5 / 6.0;
        const double log2e = 1.4426950408889634073599246810;
        bc.f0k = (float)(-betta * log2e);
        bc.kg  = (float)(2.0 * betta * delta * log2e);
        for (int b = 0; b < 6; ++b)
            bc.c[b] = (float)exp(-betta * delta * (1.0 + delta * (2*b + 1)));
        bc.scale = (float)(pow(2.0 * betta / M_PI, 0.75) / sqrt(7.0));
    }

    int prepBlocks = 448 + (natoms + 255) / 256;
    prep_kernel<<<dim3(prepBlocks), 256, 0, stream>>>(
        W1, W2, W1t, W2t, counts, (float*)d_out, natoms);

    int pgrid = (npairs + 255) / 256;
    hist_kernel<<<dim3(pgrid), 256, 0, stream>>>(R, nbr, offsets, counts, npairs);
    scan_kernel<<<dim3(1), 1024, 0, stream>>>(counts, offs, cursor, natoms);
    scatter_pair_kernel<<<dim3(pgrid), 256, 0, stream>>>(
        R, Z, nbr, offsets, emb, cursor, pairdata, npairs, bc);

    moment_kernel<<<dim3(Mpad / 4), 256, 0, stream>>>(
        pairdata, offs, counts, momG, natoms);
    feat_kernel<<<dim3(Mpad / 64), 256, 0, stream>>>(momG, feats);

    float a1 = 1.0f / sqrtf((float)NFEAT);
    float a2 = 1.0f / sqrtf((float)UNITS);
    int gemmGrid = ((Mtiles + 7) / 8) * 8 * 4;
    gemm_mfma_swish<<<dim3(gemmGrid), 256, 0, stream>>>(
        feats, W1t, b1, h1, nullptr, nullptr, KP1, natoms, Mtiles, a1, 0.f, 0);
    gemm_mfma_swish<<<dim3(gemmGrid), 256, 0, stream>>>(
        h1, W2t, b2, nullptr, W3, (float*)d_out, UNITS, natoms, Mtiles, a2, a2, 1);

    finalize_kernel<<<dim3((natoms + 255) / 256), 256, 0, stream>>>(
        (float*)d_out, Z, b3, natoms);
}